// Round 5
// baseline (345.591 us; speedup 1.0000x reference)
//
#include <hip/hip_runtime.h>
#include <math.h>

typedef __attribute__((ext_vector_type(8))) short bf16x8;   // 8 bf16 = 4 VGPRs
typedef __attribute__((ext_vector_type(4))) float f32x4;    // MFMA acc

#define NEXP 8
#define BATCH 2048

__device__ __forceinline__ unsigned short f2bf(float f) {
    union { float f; unsigned u; } v; v.f = f;
    unsigned r = v.u + 0x7FFFu + ((v.u >> 16) & 1u);   // RTNE
    return (unsigned short)(r >> 16);
}

// Fused convert: [W0|W1|W2|x] f32 -> contiguous bf16 region at dst.
#define C0 1048576   // NW0/4
#define C1 3145728   // +NW1/4
#define C2 4194304   // +NW2/4
#define C3 4456448   // +NX0/4  (total float4s; 17408 blocks * 256)
__global__ void cvt_all(const float* __restrict__ W0, const float* __restrict__ W1,
                        const float* __restrict__ W2, const float* __restrict__ x,
                        unsigned short* __restrict__ dst) {
    int i = blockIdx.x * blockDim.x + threadIdx.x;
    float4 v;
    if (i < C0)       v = ((const float4*)W0)[i];
    else if (i < C1)  v = ((const float4*)W1)[i - C0];
    else if (i < C2)  v = ((const float4*)W2)[i - C1];
    else              v = ((const float4*)x)[i - C2];
    ushort4 o;
    o.x = f2bf(v.x); o.y = f2bf(v.y); o.z = f2bf(v.z); o.w = f2bf(v.w);
    ((ushort4*)dst)[i] = o;
}

// Blended-expert layer, bf16 MFMA, NO LDS / NO BARRIERS in the K-loop.
// BM=128, BN=16*NU, BK=32, 512 threads. Wave w=(mw=w&1, ew=w>>1): owns
// m in [64*mw, 64*mw+64) x BN cols for experts {2ew, 2ew+1}.
// A-frags AND B-frags are loaded global->VGPR directly: for 16x16x32 MFMA,
// lane(ll,lh) needs W[n][k0+lh*8 .. +8] / X[m][k0+lh*8 .. +8] -- 16B
// contiguous row slices, so global_load_dwordx4 per lane gives the exact
// fragment. Register double-buffer: issue loads(k+1), MFMA(k). Waves
// free-run (no lockstep L2 bursts, no vmcnt(0) drains); W is XCD-L2
// resident, x redundancy dedups in L1.
// Epilogue (only use of LDS, 17 KB): 2-phase cross-wave blend-reduce in
// 4 t-chunks, blended bias + ELU fused.
template<int NU>
__global__ __launch_bounds__(512, 2) void moe_mfma4(
    const unsigned short* __restrict__ Xb,   // [BATCH, Din] bf16
    const unsigned short* __restrict__ Wb,   // [NEXP, Dout, Din] bf16
    const float* __restrict__ Bias,          // [NEXP, Dout]
    const float* __restrict__ WBl,           // [BATCH, NEXP]
    void* __restrict__ Yout,                 // bf16 or f32 [BATCH, Dout]
    int Din, int Dout, int act, int out_bf16)
{
    constexpr int BN   = 16 * NU;
    constexpr int PSTR = BN + 4;                     // padded f32 row stride
    __shared__ __align__(16) float lds_f[2 * 32 * PSTR];

    const int tid = threadIdx.x;
    const int w   = tid >> 6;         // 0..7
    const int l   = tid & 63;
    const int lh  = l >> 4;           // 0..3
    const int ll  = l & 15;           // 0..15
    const int mw  = w & 1;
    const int ew  = w >> 1;           // 0..3
    const int e0  = 2 * ew;
    const int m0  = blockIdx.y * 128;
    const int n0  = blockIdx.x * BN;

    f32x4 acc0[4][NU], acc1[4][NU];
    #pragma unroll
    for (int t = 0; t < 4; ++t)
        #pragma unroll
        for (int u = 0; u < NU; ++u)
            #pragma unroll
            for (int i = 0; i < 4; ++i) { acc0[t][u][i] = 0.f; acc1[t][u][i] = 0.f; }

    // byte offsets (32-bit; arrays are <32 MB)
    unsigned aoff[4], boff0[NU], boff1[NU];
    #pragma unroll
    for (int t = 0; t < 4; ++t)
        aoff[t] = ((unsigned)(m0 + 64 * mw + 16 * t + ll) * (unsigned)Din + lh * 8) * 2u;
    #pragma unroll
    for (int u = 0; u < NU; ++u) {
        boff0[u] = (((unsigned)e0 * Dout + n0 + 16 * u + ll) * (unsigned)Din + lh * 8) * 2u;
        boff1[u] = (((unsigned)(e0 + 1) * Dout + n0 + 16 * u + ll) * (unsigned)Din + lh * 8) * 2u;
    }
    const char* xc = (const char*)Xb;
    const char* wc = (const char*)Wb;

    bf16x8 aR[2][4], b0R[2][NU], b1R[2][NU];

    auto LOAD = [&](int s, unsigned kb) {
        #pragma unroll
        for (int t = 0; t < 4; ++t)
            aR[s][t] = *(const bf16x8*)(xc + aoff[t] + kb);
        #pragma unroll
        for (int u = 0; u < NU; ++u) {
            b0R[s][u] = *(const bf16x8*)(wc + boff0[u] + kb);
            b1R[s][u] = *(const bf16x8*)(wc + boff1[u] + kb);
        }
    };
    auto MF = [&](int s) {
        #pragma unroll
        for (int u = 0; u < NU; ++u)
            #pragma unroll
            for (int t = 0; t < 4; ++t) {
                acc0[t][u] = __builtin_amdgcn_mfma_f32_16x16x32_bf16(aR[s][t], b0R[s][u], acc0[t][u], 0, 0, 0);
                acc1[t][u] = __builtin_amdgcn_mfma_f32_16x16x32_bf16(aR[s][t], b1R[s][u], acc1[t][u], 0, 0, 0);
            }
    };

    const int nk = Din >> 5;          // BK=32; nk is even (16 or 32)
    LOAD(0, 0);
    for (int kk = 0; kk < nk; kk += 2) {
        const unsigned kb = (unsigned)kk << 6;       // kk*32 elems * 2B
        if (kk + 1 < nk) LOAD(1, kb + 64);
        MF(0);
        if (kk + 2 < nk) LOAD(0, kb + 128);
        MF(1);
    }

    // ---- epilogue: blended bias, cross-wave reduce in 4 t-chunks, ELU, store ----
    float bi0[NU], bi1[NU];
    #pragma unroll
    for (int u = 0; u < NU; ++u) {
        const int n = n0 + u * 16 + ll;
        bi0[u] = Bias[(size_t)e0 * Dout + n];
        bi1[u] = Bias[(size_t)(e0 + 1) * Dout + n];
    }

    float* pb0 = lds_f;
    float* pb1 = lds_f + 32 * PSTR;
    float* pb  = (ew & 2) ? pb1 : pb0;               // ew{0,1}->pb0, ew{2,3}->pb1

    // C/D layout: reg r of lane -> C[16t + 4*lh + r][16u + ll]  (m89-verified)
    #pragma unroll
    for (int t = 0; t < 4; ++t) {
        __syncthreads();                             // prev chunk fully consumed
        if (!(ew & 1)) {
            #pragma unroll
            for (int r = 0; r < 4; ++r) {
                const int lm = 16 * mw + 4 * lh + r;
                const int m  = m0 + 64 * mw + 16 * t + 4 * lh + r;
                float2 wbp = ((const float2*)(WBl + (size_t)m * NEXP))[ew];
                #pragma unroll
                for (int u = 0; u < NU; ++u)
                    pb[lm * PSTR + u * 16 + ll] =
                        wbp.x * (acc0[t][u][r] + bi0[u]) + wbp.y * (acc1[t][u][r] + bi1[u]);
            }
        }
        __syncthreads();
        if (ew & 1) {
            #pragma unroll
            for (int r = 0; r < 4; ++r) {
                const int lm = 16 * mw + 4 * lh + r;
                const int m  = m0 + 64 * mw + 16 * t + 4 * lh + r;
                float2 wbp = ((const float2*)(WBl + (size_t)m * NEXP))[ew];
                #pragma unroll
                for (int u = 0; u < NU; ++u)
                    pb[lm * PSTR + u * 16 + ll] +=
                        wbp.x * (acc0[t][u][r] + bi0[u]) + wbp.y * (acc1[t][u][r] + bi1[u]);
            }
        }
        __syncthreads();
        for (int idx = tid; idx < 32 * BN / 4; idx += 512) {
            const int row = idx / (BN / 4);
            const int c4  = (idx % (BN / 4)) * 4;
            float4 s = *(const float4*)(pb0 + row * PSTR + c4);
            float4 q = *(const float4*)(pb1 + row * PSTR + c4);
            s.x += q.x; s.y += q.y; s.z += q.z; s.w += q.w;
            if (act) {
                s.x = s.x > 0.f ? s.x : expm1f(s.x);
                s.y = s.y > 0.f ? s.y : expm1f(s.y);
                s.z = s.z > 0.f ? s.z : expm1f(s.z);
                s.w = s.w > 0.f ? s.w : expm1f(s.w);
            }
            const int m = m0 + 64 * (row >> 4) + 16 * t + (row & 15);
            const size_t off = (size_t)m * Dout + n0 + c4;
            if (out_bf16) {
                ushort4 o;
                o.x = f2bf(s.x); o.y = f2bf(s.y); o.z = f2bf(s.z); o.w = f2bf(s.w);
                *(ushort4*)((unsigned short*)Yout + off) = o;
            } else {
                *(float4*)((float*)Yout + off) = s;
            }
        }
    }
}

// ---------------- fp32 fallback for small ws_size ----------------
#define BM 64
#define BNF 64
#define BKF 16
#define PAD 4

__global__ __launch_bounds__(256) void moe_layer_f32(
    const float* __restrict__ X, const float* __restrict__ W,
    const float* __restrict__ Bias, const float* __restrict__ WB,
    float* __restrict__ Y, int Din, int Dout, int act)
{
    __shared__ float As[BKF][BM + PAD];
    __shared__ float Bs[BKF][BNF + PAD];
    const int tid = threadIdx.x;
    const int tm = tid >> 4, tn = tid & 15;
    const int m0 = blockIdx.y * BM, n0 = blockIdx.x * BNF;
    const int lr = tid >> 2, lc = (tid & 3) << 2;
    float acc[4][4] = {};
    const float* xrow  = X  + (size_t)(m0 + lr) * Din;
    const float* wbrow = WB + (size_t)(m0 + lr) * NEXP;
    const float* wrow0 = W  + (size_t)(n0 + lr) * Din;
    for (int e = 0; e < NEXP; ++e) {
        const float wbe = wbrow[e];
        const float* wrow = wrow0 + (size_t)e * Dout * Din;
        for (int k0 = 0; k0 < Din; k0 += BKF) {
            float4 av = *(const float4*)(xrow + k0 + lc);
            float4 bv = *(const float4*)(wrow + k0 + lc);
            __syncthreads();
            As[lc+0][lr] = av.x*wbe; As[lc+1][lr] = av.y*wbe;
            As[lc+2][lr] = av.z*wbe; As[lc+3][lr] = av.w*wbe;
            Bs[lc+0][lr] = bv.x; Bs[lc+1][lr] = bv.y;
            Bs[lc+2][lr] = bv.z; Bs[lc+3][lr] = bv.w;
            __syncthreads();
            #pragma unroll
            for (int k = 0; k < BKF; ++k) {
                float4 a = *(const float4*)&As[k][tm << 2];
                float4 b = *(const float4*)&Bs[k][tn << 2];
                acc[0][0]+=a.x*b.x; acc[0][1]+=a.x*b.y; acc[0][2]+=a.x*b.z; acc[0][3]+=a.x*b.w;
                acc[1][0]+=a.y*b.x; acc[1][1]+=a.y*b.y; acc[1][2]+=a.y*b.z; acc[1][3]+=a.y*b.w;
                acc[2][0]+=a.z*b.x; acc[2][1]+=a.z*b.y; acc[2][2]+=a.z*b.z; acc[2][3]+=a.z*b.w;
                acc[3][0]+=a.w*b.x; acc[3][1]+=a.w*b.y; acc[3][2]+=a.w*b.z; acc[3][3]+=a.w*b.w;
            }
        }
    }
    #pragma unroll
    for (int im = 0; im < 4; ++im) {
        const int m = m0 + (tm << 2) + im;
        const float* wbm = WB + (size_t)m * NEXP;
        float wv[NEXP];
        #pragma unroll
        for (int e = 0; e < NEXP; ++e) wv[e] = wbm[e];
        #pragma unroll
        for (int in = 0; in < 4; ++in) {
            const int n = n0 + (tn << 2) + in;
            float bsum = 0.f;
            #pragma unroll
            for (int e = 0; e < NEXP; ++e) bsum += wv[e] * Bias[(size_t)e * Dout + n];
            float v = acc[im][in] + bsum;
            if (act) v = v > 0.f ? v : expm1f(v);
            acc[im][in] = v;
        }
        float4 o = make_float4(acc[im][0], acc[im][1], acc[im][2], acc[im][3]);
        *(float4*)(Y + (size_t)m * Dout + n0 + (tn << 2)) = o;
    }
}

extern "C" void kernel_launch(void* const* d_in, const int* in_sizes, int n_in,
                              void* d_out, int out_size, void* d_ws, size_t ws_size,
                              hipStream_t stream)
{
    (void)in_sizes; (void)n_in; (void)out_size;
    const float* wb = (const float*)d_in[0];
    const float* x  = (const float*)d_in[1];
    const float* W0 = (const float*)d_in[2];
    const float* B0 = (const float*)d_in[3];
    const float* W1 = (const float*)d_in[4];
    const float* B1 = (const float*)d_in[5];
    const float* W2 = (const float*)d_in[6];
    const float* B2 = (const float*)d_in[7];
    float* out = (float*)d_out;

    const size_t NW0 = (size_t)8*1024*512, NW1 = (size_t)8*1024*1024, NW2 = (size_t)8*512*1024;
    const size_t NX0 = (size_t)BATCH*512, NX1 = (size_t)BATCH*1024;
    const size_t need = (NW0 + NW1 + NW2 + NX0 + 2 * NX1) * 2;   // ~44 MB bf16

    if (ws_size >= need) {
        unsigned short* Wb0 = (unsigned short*)d_ws;
        unsigned short* Wb1 = Wb0 + NW0;
        unsigned short* Wb2 = Wb1 + NW1;
        unsigned short* xb0 = Wb2 + NW2;
        unsigned short* xb1 = xb0 + NX0;
        unsigned short* xb2 = xb1 + NX1;
        cvt_all<<<C3 / 256, 256, 0, stream>>>(W0, W1, W2, x, Wb0);
        moe_mfma4<4><<<dim3(16, 16), 512, 0, stream>>>(xb0, Wb0, B0, wb, xb1, 512,  1024, 1, 1);
        moe_mfma4<4><<<dim3(16, 16), 512, 0, stream>>>(xb1, Wb1, B1, wb, xb2, 1024, 1024, 1, 1);
        moe_mfma4<2><<<dim3(16, 16), 512, 0, stream>>>(xb2, Wb2, B2, wb, out, 1024, 512,  0, 0);
    } else {
        float* x1 = (float*)d_ws;
        float* x2 = x1 + (size_t)BATCH * 1024;
        moe_layer_f32<<<dim3(1024/BNF, BATCH/BM), 256, 0, stream>>>(x,  W0, B0, wb, x1, 512,  1024, 1);
        moe_layer_f32<<<dim3(1024/BNF, BATCH/BM), 256, 0, stream>>>(x1, W1, B1, wb, x2, 1024, 1024, 1);
        moe_layer_f32<<<dim3(512/BNF,  BATCH/BM), 256, 0, stream>>>(x2, W2, B2, wb, out, 1024, 512,  0);
    }
}

// Round 6
// 202.300 us; speedup vs baseline: 1.7083x; 1.7083x over previous
//
#include <hip/hip_runtime.h>
#include <math.h>

typedef __attribute__((ext_vector_type(8))) short bf16x8;   // 8 bf16 = 4 VGPRs
typedef __attribute__((ext_vector_type(4))) float f32x4;    // MFMA acc

#define NEXP 8
#define BATCH 2048

__device__ __forceinline__ unsigned short f2bf(float f) {
    union { float f; unsigned u; } v; v.f = f;
    unsigned r = v.u + 0x7FFFu + ((v.u >> 16) & 1u);   // RTNE
    return (unsigned short)(r >> 16);
}

// ---------------------------------------------------------------------------
// Fragment-packing converter. Packs f32 W/x into bf16 MFMA-fragment order so
// every GEMM load is 1 KB fully contiguous (kills the 16x64B gather that
// capped all prior rounds at ~4.3 cyc per 64B L2 segment).
// W layout: tile lin = (nb*KB + kb)*8 + e; tile = U frags x 64 lanes x 16B;
//   frag (u, lane l): W[e][nb*16U + u*16 + (l&15)][kb*32 + (l>>4)*8 .. +8]
// x layout: tile lin = mb*16 + kb; 8 frags g=(mw*4+t): lane l:
//   x[mb*128 + g*16 + (l&15)][kb*32 + (l>>4)*8 .. +8]
// Tile ranges: [0,2048) W0(U4,KB16), [2048,6144) W1(U4,KB32),
//              [6144,10240) W2(U2,KB32), [10240,10496) x.
// ---------------------------------------------------------------------------
__global__ __launch_bounds__(256) void pack_all(
    const float* __restrict__ W0, const float* __restrict__ W1,
    const float* __restrict__ W2, const float* __restrict__ x,
    unsigned short* __restrict__ W0p, unsigned short* __restrict__ W1p,
    unsigned short* __restrict__ W2p, unsigned short* __restrict__ x0p)
{
    __shared__ float T[128 * 36];                 // padded row stride 36 (144B)
    const int bid = blockIdx.x, t = threadIdx.x;

    if (bid < 10240) {
        const float* W; unsigned short* out; int KB, Din, Dout, U, lin;
        if (bid < 2048)      { W = W0; out = W0p; KB = 16; Din = 512;  Dout = 1024; U = 4; lin = bid; }
        else if (bid < 6144) { W = W1; out = W1p; KB = 32; Din = 1024; Dout = 1024; U = 4; lin = bid - 2048; }
        else                 { W = W2; out = W2p; KB = 32; Din = 1024; Dout = 512;  U = 2; lin = bid - 6144; }
        const int e  = lin & 7;
        const int r  = lin >> 3;                  // nb*KB + kb
        const int kb = r % KB;
        const int nb = r / KB;
        const int N0 = nb * 16 * U;
        const int K0 = kb * 32;
        for (int it = 0; it < U / 2; ++it) {      // read 16U x 32 f32, coalesced rows
            const int idx = t + 256 * it;         // < 128*U
            const int nl = idx >> 3, k4 = (idx & 7) * 4;
            float4 v = *(const float4*)(W + ((size_t)e * Dout + N0 + nl) * Din + K0 + k4);
            *(float4*)(T + nl * 36 + k4) = v;
        }
        __syncthreads();
        if (t < 64 * U) {
            const int u = t >> 6, l = t & 63;
            const float* p = T + (u * 16 + (l & 15)) * 36 + (l >> 4) * 8;
            bf16x8 h;
            #pragma unroll
            for (int j = 0; j < 8; ++j) h[j] = (short)f2bf(p[j]);
            *(bf16x8*)(out + (size_t)lin * (U * 512) + t * 8) = h;   // coalesced 16B/thread
        }
    } else {
        const int lin = bid - 10240;              // mb*16 + kb   (KB=16, Din=512)
        const int kb = lin & 15, mb = lin >> 4;
        for (int it = 0; it < 4; ++it) {          // 128 x 32 f32
            const int idx = t + 256 * it;
            const int ml = idx >> 3, k4 = (idx & 7) * 4;
            float4 v = *(const float4*)(x + (size_t)(mb * 128 + ml) * 512 + kb * 32 + k4);
            *(float4*)(T + ml * 36 + k4) = v;
        }
        __syncthreads();
        #pragma unroll
        for (int it = 0; it < 2; ++it) {
            const int s = t + 256 * it;           // < 512 frag-lane slots
            const int g = s >> 6, l = s & 63;
            const float* p = T + (g * 16 + (l & 15)) * 36 + (l >> 4) * 8;
            bf16x8 h;
            #pragma unroll
            for (int j = 0; j < 8; ++j) h[j] = (short)f2bf(p[j]);
            *(bf16x8*)(x0p + (size_t)lin * 4096 + s * 8) = h;
        }
    }
}

// ---------------------------------------------------------------------------
// Blended-expert layer, bf16 MFMA, packed operands, NO LDS/barriers in K-loop.
// BM=128, BN=16*NU, BK=32, 512 threads. Wave (mw=w&1, ew=w>>1): owns
// m in [64mw, 64mw+64) x BN cols for experts {2ew, 2ew+1}. All frag loads are
// 1 KB contiguous global->VGPR (lane i -> base + 16i), register double-buffer.
// Epilogue: cross-wave LDS blend-reduce (17 KB), bias+ELU fused; output is
// written PACKED (next layer's A-frags) or f32 row-major (last layer).
// ---------------------------------------------------------------------------
template<int NU>
__global__ __launch_bounds__(512, 2) void moe_mfma5(
    const unsigned short* __restrict__ Xp,   // packed A frags
    const unsigned short* __restrict__ Wp,   // packed B frags
    const float* __restrict__ Bias,          // [NEXP, Dout]
    const float* __restrict__ WBl,           // [BATCH, NEXP]
    void* __restrict__ Yout,                 // packed bf16 or f32 row-major
    int KB, int Dout, int KBn, int act, int packed_out)
{
    constexpr int BN   = 16 * NU;
    constexpr int PSTR = BN + 4;
    __shared__ __align__(16) float lds_f[2 * 32 * PSTR];

    const int tid = threadIdx.x;
    const int w   = tid >> 6;
    const int l   = tid & 63;
    const int lh  = l >> 4;
    const int ll  = l & 15;
    const int mw  = w & 1;
    const int ew  = w >> 1;
    const int e0  = 2 * ew;
    const int by  = blockIdx.y;               // m0 = by*128
    const int bx  = blockIdx.x;               // n0 = bx*BN
    const int m0  = by * 128;
    const int n0  = bx * BN;

    f32x4 acc0[4][NU], acc1[4][NU];
    #pragma unroll
    for (int t = 0; t < 4; ++t)
        #pragma unroll
        for (int u = 0; u < NU; ++u)
            #pragma unroll
            for (int i = 0; i < 4; ++i) { acc0[t][u][i] = 0.f; acc1[t][u][i] = 0.f; }

    // packed byte offsets at kk=0
    unsigned aoff[4], boff0[NU], boff1[NU];
    #pragma unroll
    for (int t = 0; t < 4; ++t)
        aoff[t] = ((unsigned)(by * KB) * 8 + mw * 4 + t) * 1024u + l * 16u;
    #pragma unroll
    for (int u = 0; u < NU; ++u) {
        boff0[u] = ((unsigned)(bx * KB) * (8 * NU) + e0 * NU + u) * 1024u + l * 16u;
        boff1[u] = boff0[u] + NU * 1024u;
    }
    const char* xc = (const char*)Xp;
    const char* wc = (const char*)Wp;

    bf16x8 aR[2][4], b0R[2][NU], b1R[2][NU];

    auto LOAD = [&](int s, int kk) {
        const unsigned ab = (unsigned)kk * 8192u;
        const unsigned bb = (unsigned)kk * (8192u * NU);
        #pragma unroll
        for (int t = 0; t < 4; ++t)
            aR[s][t] = *(const bf16x8*)(xc + aoff[t] + ab);
        #pragma unroll
        for (int u = 0; u < NU; ++u) {
            b0R[s][u] = *(const bf16x8*)(wc + boff0[u] + bb);
            b1R[s][u] = *(const bf16x8*)(wc + boff1[u] + bb);
        }
    };
    auto MF = [&](int s) {
        #pragma unroll
        for (int u = 0; u < NU; ++u)
            #pragma unroll
            for (int t = 0; t < 4; ++t) {
                acc0[t][u] = __builtin_amdgcn_mfma_f32_16x16x32_bf16(aR[s][t], b0R[s][u], acc0[t][u], 0, 0, 0);
                acc1[t][u] = __builtin_amdgcn_mfma_f32_16x16x32_bf16(aR[s][t], b1R[s][u], acc1[t][u], 0, 0, 0);
            }
    };

    LOAD(0, 0);
    for (int kk = 0; kk < KB; kk += 2) {
        if (kk + 1 < KB) LOAD(1, kk + 1);
        MF(0);
        if (kk + 2 < KB) LOAD(0, kk + 2);
        MF(1);
    }

    // ---- epilogue ----
    float bi0[NU], bi1[NU];
    #pragma unroll
    for (int u = 0; u < NU; ++u) {
        const int n = n0 + u * 16 + ll;
        bi0[u] = Bias[(size_t)e0 * Dout + n];
        bi1[u] = Bias[(size_t)(e0 + 1) * Dout + n];
    }

    float* pb0 = lds_f;
    float* pb1 = lds_f + 32 * PSTR;
    float* pb  = (ew & 2) ? pb1 : pb0;

    // C/D layout: reg r of lane -> C[16t + 4*lh + r][16u + ll]  (m89-verified)
    #pragma unroll
    for (int tc = 0; tc < 4; ++tc) {
        __syncthreads();
        if (!(ew & 1)) {
            #pragma unroll
            for (int r = 0; r < 4; ++r) {
                const int lm = 16 * mw + 4 * lh + r;
                const int m  = m0 + 64 * mw + 16 * tc + 4 * lh + r;
                float2 wbp = ((const float2*)(WBl + (size_t)m * NEXP))[ew];
                #pragma unroll
                for (int u = 0; u < NU; ++u)
                    pb[lm * PSTR + u * 16 + ll] =
                        wbp.x * (acc0[tc][u][r] + bi0[u]) + wbp.y * (acc1[tc][u][r] + bi1[u]);
            }
        }
        __syncthreads();
        if (ew & 1) {
            #pragma unroll
            for (int r = 0; r < 4; ++r) {
                const int lm = 16 * mw + 4 * lh + r;
                const int m  = m0 + 64 * mw + 16 * tc + 4 * lh + r;
                float2 wbp = ((const float2*)(WBl + (size_t)m * NEXP))[ew];
                #pragma unroll
                for (int u = 0; u < NU; ++u)
                    pb[lm * PSTR + u * 16 + ll] +=
                        wbp.x * (acc0[tc][u][r] + bi0[u]) + wbp.y * (acc1[tc][u][r] + bi1[u]);
            }
        }
        __syncthreads();
        if (packed_out) {
            // write next-layer A-frags: slots (kb_loc, mw, lane), 16B each
            const int s = tid;
            if (s < NU * 64) {
                const int kb_loc = s >> 7;            // 0..NU/2-1
                const int mwq    = (s >> 6) & 1;
                const int sl     = s & 63;
                const int lm     = mwq * 16 + (sl & 15);
                const int c0     = kb_loc * 32 + (sl >> 4) * 8;
                bf16x8 h;
                #pragma unroll
                for (int j = 0; j < 8; ++j) {
                    float v = pb0[lm * PSTR + c0 + j] + pb1[lm * PSTR + c0 + j];
                    v = v > 0.f ? v : expm1f(v);      // packed layers always ELU
                    h[j] = (short)f2bf(v);
                }
                const unsigned dst =
                    (((unsigned)by * KBn + (n0 >> 5) + kb_loc) * 8 + mwq * 4 + tc) * 1024u
                    + (unsigned)sl * 16u;
                *(bf16x8*)((char*)Yout + dst) = h;
            }
        } else {
            for (int idx = tid; idx < 32 * BN / 4; idx += 512) {
                const int row = idx / (BN / 4);
                const int c4  = (idx % (BN / 4)) * 4;
                float4 sv = *(const float4*)(pb0 + row * PSTR + c4);
                float4 qv = *(const float4*)(pb1 + row * PSTR + c4);
                sv.x += qv.x; sv.y += qv.y; sv.z += qv.z; sv.w += qv.w;
                if (act) {
                    sv.x = sv.x > 0.f ? sv.x : expm1f(sv.x);
                    sv.y = sv.y > 0.f ? sv.y : expm1f(sv.y);
                    sv.z = sv.z > 0.f ? sv.z : expm1f(sv.z);
                    sv.w = sv.w > 0.f ? sv.w : expm1f(sv.w);
                }
                const int m = m0 + 64 * (row >> 4) + 16 * tc + (row & 15);
                *(float4*)((float*)Yout + (size_t)m * Dout + n0 + c4) = sv;
            }
        }
    }
}

// ---------------- fp32 fallback for small ws_size ----------------
#define BM 64
#define BNF 64
#define BKF 16
#define PAD 4

__global__ __launch_bounds__(256) void moe_layer_f32(
    const float* __restrict__ X, const float* __restrict__ W,
    const float* __restrict__ Bias, const float* __restrict__ WB,
    float* __restrict__ Y, int Din, int Dout, int act)
{
    __shared__ float As[BKF][BM + PAD];
    __shared__ float Bs[BKF][BNF + PAD];
    const int tid = threadIdx.x;
    const int tm = tid >> 4, tn = tid & 15;
    const int m0 = blockIdx.y * BM, n0 = blockIdx.x * BNF;
    const int lr = tid >> 2, lc = (tid & 3) << 2;
    float acc[4][4] = {};
    const float* xrow  = X  + (size_t)(m0 + lr) * Din;
    const float* wbrow = WB + (size_t)(m0 + lr) * NEXP;
    const float* wrow0 = W  + (size_t)(n0 + lr) * Din;
    for (int e = 0; e < NEXP; ++e) {
        const float wbe = wbrow[e];
        const float* wrow = wrow0 + (size_t)e * Dout * Din;
        for (int k0 = 0; k0 < Din; k0 += BKF) {
            float4 av = *(const float4*)(xrow + k0 + lc);
            float4 bv = *(const float4*)(wrow + k0 + lc);
            __syncthreads();
            As[lc+0][lr] = av.x*wbe; As[lc+1][lr] = av.y*wbe;
            As[lc+2][lr] = av.z*wbe; As[lc+3][lr] = av.w*wbe;
            Bs[lc+0][lr] = bv.x; Bs[lc+1][lr] = bv.y;
            Bs[lc+2][lr] = bv.z; Bs[lc+3][lr] = bv.w;
            __syncthreads();
            #pragma unroll
            for (int k = 0; k < BKF; ++k) {
                float4 a = *(const float4*)&As[k][tm << 2];
                float4 b = *(const float4*)&Bs[k][tn << 2];
                acc[0][0]+=a.x*b.x; acc[0][1]+=a.x*b.y; acc[0][2]+=a.x*b.z; acc[0][3]+=a.x*b.w;
                acc[1][0]+=a.y*b.x; acc[1][1]+=a.y*b.y; acc[1][2]+=a.y*b.z; acc[1][3]+=a.y*b.w;
                acc[2][0]+=a.z*b.x; acc[2][1]+=a.z*b.y; acc[2][2]+=a.z*b.z; acc[2][3]+=a.z*b.w;
                acc[3][0]+=a.w*b.x; acc[3][1]+=a.w*b.y; acc[3][2]+=a.w*b.z; acc[3][3]+=a.w*b.w;
            }
        }
    }
    #pragma unroll
    for (int im = 0; im < 4; ++im) {
        const int m = m0 + (tm << 2) + im;
        const float* wbm = WB + (size_t)m * NEXP;
        float wv[NEXP];
        #pragma unroll
        for (int e = 0; e < NEXP; ++e) wv[e] = wbm[e];
        #pragma unroll
        for (int in = 0; in < 4; ++in) {
            const int n = n0 + (tn << 2) + in;
            float bsum = 0.f;
            #pragma unroll
            for (int e = 0; e < NEXP; ++e) bsum += wv[e] * Bias[(size_t)e * Dout + n];
            float v = acc[im][in] + bsum;
            if (act) v = v > 0.f ? v : expm1f(v);
            acc[im][in] = v;
        }
        float4 o = make_float4(acc[im][0], acc[im][1], acc[im][2], acc[im][3]);
        *(float4*)(Y + (size_t)m * Dout + n0 + (tn << 2)) = o;
    }
}

extern "C" void kernel_launch(void* const* d_in, const int* in_sizes, int n_in,
                              void* d_out, int out_size, void* d_ws, size_t ws_size,
                              hipStream_t stream)
{
    (void)in_sizes; (void)n_in; (void)out_size;
    const float* wb = (const float*)d_in[0];
    const float* x  = (const float*)d_in[1];
    const float* W0 = (const float*)d_in[2];
    const float* B0 = (const float*)d_in[3];
    const float* W1 = (const float*)d_in[4];
    const float* B1 = (const float*)d_in[5];
    const float* W2 = (const float*)d_in[6];
    const float* B2 = (const float*)d_in[7];
    float* out = (float*)d_out;

    const size_t NW0 = (size_t)8*1024*512, NW1 = (size_t)8*1024*1024, NW2 = (size_t)8*512*1024;
    const size_t NX0 = (size_t)BATCH*512, NX1 = (size_t)BATCH*1024;
    const size_t need = (NW0 + NW1 + NW2 + NX0 + 2 * NX1) * 2;   // ~44 MB bf16

    if (ws_size >= need) {
        unsigned short* W0p = (unsigned short*)d_ws;
        unsigned short* W1p = W0p + NW0;
        unsigned short* W2p = W1p + NW1;
        unsigned short* x0p = W2p + NW2;
        unsigned short* x1p = x0p + NX0;
        unsigned short* x2p = x1p + NX1;
        pack_all<<<10496, 256, 0, stream>>>(W0, W1, W2, x, W0p, W1p, W2p, x0p);
        moe_mfma5<4><<<dim3(16, 16), 512, 0, stream>>>(x0p, W0p, B0, wb, x1p, 16, 1024, 32, 1, 1);
        moe_mfma5<4><<<dim3(16, 16), 512, 0, stream>>>(x1p, W1p, B1, wb, x2p, 32, 1024, 32, 1, 1);
        moe_mfma5<2><<<dim3(16, 16), 512, 0, stream>>>(x2p, W2p, B2, wb, out, 32, 512,  0, 0, 0);
    } else {
        float* x1 = (float*)d_ws;
        float* x2 = x1 + (size_t)BATCH * 1024;
        moe_layer_f32<<<dim3(1024/BNF, BATCH/BM), 256, 0, stream>>>(x,  W0, B0, wb, x1, 512,  1024, 1);
        moe_layer_f32<<<dim3(1024/BNF, BATCH/BM), 256, 0, stream>>>(x1, W1, B1, wb, x2, 1024, 1024, 1);
        moe_layer_f32<<<dim3(512/BNF,  BATCH/BM), 256, 0, stream>>>(x2, W2, B2, wb, out, 1024, 512,  0);
    }
}

// Round 7
// 201.762 us; speedup vs baseline: 1.7129x; 1.0027x over previous
//
#include <hip/hip_runtime.h>
#include <math.h>

typedef __attribute__((ext_vector_type(8))) short bf16x8;   // 8 bf16 = 4 VGPRs
typedef __attribute__((ext_vector_type(4))) float f32x4;    // MFMA acc

#define NEXP 8
#define BATCH 2048

__device__ __forceinline__ unsigned short f2bf(float f) {
    union { float f; unsigned u; } v; v.f = f;
    unsigned r = v.u + 0x7FFFu + ((v.u >> 16) & 1u);   // RTNE
    return (unsigned short)(r >> 16);
}

// ---------------------------------------------------------------------------
// Fragment-packing converter (unchanged from R6). Packs f32 W/x into bf16
// MFMA-fragment order so every GEMM load is 1 KB contiguous.
// W: tile lin = (nb*KB + kb)*8 + e; frag (u, lane l):
//   W[e][nb*16U + u*16 + (l&15)][kb*32 + (l>>4)*8 .. +8]
// x: tile lin = mb*16 + kb; frag g: x[mb*128 + g*16 + (l&15)][kb*32+(l>>4)*8..]
// ---------------------------------------------------------------------------
__global__ __launch_bounds__(256) void pack_all(
    const float* __restrict__ W0, const float* __restrict__ W1,
    const float* __restrict__ W2, const float* __restrict__ x,
    unsigned short* __restrict__ W0p, unsigned short* __restrict__ W1p,
    unsigned short* __restrict__ W2p, unsigned short* __restrict__ x0p)
{
    __shared__ float T[128 * 36];
    const int bid = blockIdx.x, t = threadIdx.x;

    if (bid < 10240) {
        const float* W; unsigned short* out; int KB, Din, Dout, U, lin;
        if (bid < 2048)      { W = W0; out = W0p; KB = 16; Din = 512;  Dout = 1024; U = 4; lin = bid; }
        else if (bid < 6144) { W = W1; out = W1p; KB = 32; Din = 1024; Dout = 1024; U = 4; lin = bid - 2048; }
        else                 { W = W2; out = W2p; KB = 32; Din = 1024; Dout = 512;  U = 2; lin = bid - 6144; }
        const int e  = lin & 7;
        const int r  = lin >> 3;
        const int kb = r % KB;
        const int nb = r / KB;
        const int N0 = nb * 16 * U;
        const int K0 = kb * 32;
        for (int it = 0; it < U / 2; ++it) {
            const int idx = t + 256 * it;
            const int nl = idx >> 3, k4 = (idx & 7) * 4;
            float4 v = *(const float4*)(W + ((size_t)e * Dout + N0 + nl) * Din + K0 + k4);
            *(float4*)(T + nl * 36 + k4) = v;
        }
        __syncthreads();
        if (t < 64 * U) {
            const int u = t >> 6, l = t & 63;
            const float* p = T + (u * 16 + (l & 15)) * 36 + (l >> 4) * 8;
            bf16x8 h;
            #pragma unroll
            for (int j = 0; j < 8; ++j) h[j] = (short)f2bf(p[j]);
            *(bf16x8*)(out + (size_t)lin * (U * 512) + t * 8) = h;
        }
    } else {
        const int lin = bid - 10240;
        const int kb = lin & 15, mb = lin >> 4;
        for (int it = 0; it < 4; ++it) {
            const int idx = t + 256 * it;
            const int ml = idx >> 3, k4 = (idx & 7) * 4;
            float4 v = *(const float4*)(x + (size_t)(mb * 128 + ml) * 512 + kb * 32 + k4);
            *(float4*)(T + ml * 36 + k4) = v;
        }
        __syncthreads();
        #pragma unroll
        for (int it = 0; it < 2; ++it) {
            const int s = t + 256 * it;
            const int g = s >> 6, l = s & 63;
            const float* p = T + (g * 16 + (l & 15)) * 36 + (l >> 4) * 8;
            bf16x8 h;
            #pragma unroll
            for (int j = 0; j < 8; ++j) h[j] = (short)f2bf(p[j]);
            *(bf16x8*)(x0p + (size_t)lin * 4096 + s * 8) = h;
        }
    }
}

// ---------------------------------------------------------------------------
// Blended-expert layer, bf16 MFMA, packed operands, small-state high-occupancy.
// 256 threads = 4 waves. Wave ew owns experts {2ew, 2ew+1} over the FULL
// 64m x 32n block tile (acc = 16 f32x4 = 64 regs). Frags double-buffered
// (64 regs). Target 3 blocks/CU (3 waves/SIMD) for latency hiding; all loads
// 1 KB contiguous global->VGPR. Grid: (Dout/32, 2048/64).
// Epilogue: 2-buf 2-phase cross-wave blend reduce (18 KB LDS), bias + ELU
// folded; output written packed (next layer A-frags) or f32 row-major.
// UP = pack-width U of the weight tiles this layer reads (4 or 2).
// ---------------------------------------------------------------------------
template<int UP>
__global__ __launch_bounds__(256, 3) void moe_mfma6(
    const unsigned short* __restrict__ Xp,   // packed A frags
    const unsigned short* __restrict__ Wp,   // packed B frags (U=UP)
    const float* __restrict__ Bias,          // [NEXP, Dout]
    const float* __restrict__ WBl,           // [BATCH, NEXP]
    void* __restrict__ Yout,                 // packed bf16 or f32 row-major
    int KB, int Dout, int KBn, int act, int packed_out)
{
    constexpr int PSTR = 36;                 // padded f32 row stride
    __shared__ __align__(16) float lds_f[2 * 64 * PSTR];   // 18 KB

    const int tid  = threadIdx.x;
    const int ew   = tid >> 6;               // 0..3 -> experts {2ew, 2ew+1}
    const int l    = tid & 63;
    const int lh   = l >> 4;
    const int ll   = l & 15;
    const int e0   = 2 * ew;
    const int bx   = blockIdx.x;             // n0 = bx*32
    const int by   = blockIdx.y;             // m0 = by*64
    const int m0   = by * 64;
    const int n0   = bx * 32;
    const int mb   = by >> 1;                // 128-row pack group
    const int half = by & 1;

    f32x4 acc0[4][2], acc1[4][2];
    #pragma unroll
    for (int t = 0; t < 4; ++t)
        #pragma unroll
        for (int u = 0; u < 2; ++u)
            #pragma unroll
            for (int i = 0; i < 4; ++i) { acc0[t][u][i] = 0.f; acc1[t][u][i] = 0.f; }

    // packed byte offsets at kk=0
    unsigned aoff[4];
    #pragma unroll
    for (int t = 0; t < 4; ++t)
        aoff[t] = (unsigned)(mb * KB) * 8192u + (unsigned)(half * 4 + t) * 1024u + l * 16u;
    const int nb   = (bx * 2) / UP;
    const int uoff = (bx * 2) % UP;
    unsigned boff0[2], boff1[2];
    #pragma unroll
    for (int u = 0; u < 2; ++u) {
        boff0[u] = (((unsigned)(nb * KB) * 8 + e0) * UP + uoff + u) * 1024u + l * 16u;
        boff1[u] = boff0[u] + UP * 1024u;
    }
    const unsigned astr = 8192u;
    const unsigned bstr = UP * 8192u;
    const char* xc = (const char*)Xp;
    const char* wc = (const char*)Wp;

    bf16x8 aR[2][4], b0R[2][2], b1R[2][2];

    auto LOAD = [&](int s, int kk) {
        const unsigned ab = (unsigned)kk * astr;
        const unsigned bb = (unsigned)kk * bstr;
        #pragma unroll
        for (int t = 0; t < 4; ++t)
            aR[s][t] = *(const bf16x8*)(xc + aoff[t] + ab);
        #pragma unroll
        for (int u = 0; u < 2; ++u) {
            b0R[s][u] = *(const bf16x8*)(wc + boff0[u] + bb);
            b1R[s][u] = *(const bf16x8*)(wc + boff1[u] + bb);
        }
    };
    auto MF = [&](int s) {
        #pragma unroll
        for (int u = 0; u < 2; ++u)
            #pragma unroll
            for (int t = 0; t < 4; ++t) {
                acc0[t][u] = __builtin_amdgcn_mfma_f32_16x16x32_bf16(aR[s][t], b0R[s][u], acc0[t][u], 0, 0, 0);
                acc1[t][u] = __builtin_amdgcn_mfma_f32_16x16x32_bf16(aR[s][t], b1R[s][u], acc1[t][u], 0, 0, 0);
            }
    };

    LOAD(0, 0);
    for (int kk = 0; kk < KB; kk += 2) {     // KB is even (16 or 32)
        if (kk + 1 < KB) LOAD(1, kk + 1);
        MF(0);
        if (kk + 2 < KB) LOAD(0, kk + 2);
        MF(1);
    }

    // ---- epilogue: per-expert bias + blend, 2-phase reduce, act, store ----
    float bi0[2], bi1[2];
    #pragma unroll
    for (int u = 0; u < 2; ++u) {
        const int n = n0 + u * 16 + ll;
        bi0[u] = Bias[(size_t)e0 * Dout + n];
        bi1[u] = Bias[(size_t)(e0 + 1) * Dout + n];
    }

    float* pb = lds_f + (ew & 1) * (64 * PSTR);

    // C/D layout: reg r of lane -> C[16t + 4*lh + r][16u + ll]  (m89-verified)
    if (ew < 2) {
        #pragma unroll
        for (int t = 0; t < 4; ++t)
            #pragma unroll
            for (int r = 0; r < 4; ++r) {
                const int lm = 16 * t + 4 * lh + r;
                float2 wbp = ((const float2*)(WBl + (size_t)(m0 + lm) * NEXP))[ew];
                #pragma unroll
                for (int u = 0; u < 2; ++u)
                    pb[lm * PSTR + u * 16 + ll] =
                        wbp.x * (acc0[t][u][r] + bi0[u]) + wbp.y * (acc1[t][u][r] + bi1[u]);
            }
    }
    __syncthreads();
    if (ew >= 2) {
        #pragma unroll
        for (int t = 0; t < 4; ++t)
            #pragma unroll
            for (int r = 0; r < 4; ++r) {
                const int lm = 16 * t + 4 * lh + r;
                float2 wbp = ((const float2*)(WBl + (size_t)(m0 + lm) * NEXP))[ew];
                #pragma unroll
                for (int u = 0; u < 2; ++u)
                    pb[lm * PSTR + u * 16 + ll] +=
                        wbp.x * (acc0[t][u][r] + bi0[u]) + wbp.y * (acc1[t][u][r] + bi1[u]);
            }
    }
    __syncthreads();

    float* pb0 = lds_f;
    float* pb1 = lds_f + 64 * PSTR;
    if (packed_out) {
        // thread = (g = tid>>6, lane l): next-layer A-frag, 16B per thread
        const int g  = tid >> 6;
        const int c0 = lh * 8;
        const int rowbase = (g * 16 + ll) * PSTR;
        bf16x8 h;
        #pragma unroll
        for (int j = 0; j < 8; ++j) {
            float v = pb0[rowbase + c0 + j] + pb1[rowbase + c0 + j];
            if (act) v = v > 0.f ? v : expm1f(v);
            h[j] = (short)f2bf(v);
        }
        unsigned short* dst = (unsigned short*)Yout +
            ((size_t)(mb * KBn + bx) * 8 + half * 4 + g) * 512 + l * 8;
        *(bf16x8*)dst = h;
    } else {
        #pragma unroll
        for (int it = 0; it < 2; ++it) {
            const int idx = tid + 256 * it;          // 512 float4 slots (64x32)
            const int row = idx >> 3;
            const int c4  = (idx & 7) * 4;
            float4 s = *(const float4*)(pb0 + row * PSTR + c4);
            float4 q = *(const float4*)(pb1 + row * PSTR + c4);
            s.x += q.x; s.y += q.y; s.z += q.z; s.w += q.w;
            if (act) {
                s.x = s.x > 0.f ? s.x : expm1f(s.x);
                s.y = s.y > 0.f ? s.y : expm1f(s.y);
                s.z = s.z > 0.f ? s.z : expm1f(s.z);
                s.w = s.w > 0.f ? s.w : expm1f(s.w);
            }
            *(float4*)((float*)Yout + (size_t)(m0 + row) * Dout + n0 + c4) = s;
        }
    }
}

// ---------------- fp32 fallback for small ws_size ----------------
#define BM 64
#define BNF 64
#define BKF 16
#define PAD 4

__global__ __launch_bounds__(256) void moe_layer_f32(
    const float* __restrict__ X, const float* __restrict__ W,
    const float* __restrict__ Bias, const float* __restrict__ WB,
    float* __restrict__ Y, int Din, int Dout, int act)
{
    __shared__ float As[BKF][BM + PAD];
    __shared__ float Bs[BKF][BNF + PAD];
    const int tid = threadIdx.x;
    const int tm = tid >> 4, tn = tid & 15;
    const int m0 = blockIdx.y * BM, n0 = blockIdx.x * BNF;
    const int lr = tid >> 2, lc = (tid & 3) << 2;
    float acc[4][4] = {};
    const float* xrow  = X  + (size_t)(m0 + lr) * Din;
    const float* wbrow = WB + (size_t)(m0 + lr) * NEXP;
    const float* wrow0 = W  + (size_t)(n0 + lr) * Din;
    for (int e = 0; e < NEXP; ++e) {
        const float wbe = wbrow[e];
        const float* wrow = wrow0 + (size_t)e * Dout * Din;
        for (int k0 = 0; k0 < Din; k0 += BKF) {
            float4 av = *(const float4*)(xrow + k0 + lc);
            float4 bv = *(const float4*)(wrow + k0 + lc);
            __syncthreads();
            As[lc+0][lr] = av.x*wbe; As[lc+1][lr] = av.y*wbe;
            As[lc+2][lr] = av.z*wbe; As[lc+3][lr] = av.w*wbe;
            Bs[lc+0][lr] = bv.x; Bs[lc+1][lr] = bv.y;
            Bs[lc+2][lr] = bv.z; Bs[lc+3][lr] = bv.w;
            __syncthreads();
            #pragma unroll
            for (int k = 0; k < BKF; ++k) {
                float4 a = *(const float4*)&As[k][tm << 2];
                float4 b = *(const float4*)&Bs[k][tn << 2];
                acc[0][0]+=a.x*b.x; acc[0][1]+=a.x*b.y; acc[0][2]+=a.x*b.z; acc[0][3]+=a.x*b.w;
                acc[1][0]+=a.y*b.x; acc[1][1]+=a.y*b.y; acc[1][2]+=a.y*b.z; acc[1][3]+=a.y*b.w;
                acc[2][0]+=a.z*b.x; acc[2][1]+=a.z*b.y; acc[2][2]+=a.z*b.z; acc[2][3]+=a.z*b.w;
                acc[3][0]+=a.w*b.x; acc[3][1]+=a.w*b.y; acc[3][2]+=a.w*b.z; acc[3][3]+=a.w*b.w;
            }
        }
    }
    #pragma unroll
    for (int im = 0; im < 4; ++im) {
        const int m = m0 + (tm << 2) + im;
        const float* wbm = WB + (size_t)m * NEXP;
        float wv[NEXP];
        #pragma unroll
        for (int e = 0; e < NEXP; ++e) wv[e] = wbm[e];
        #pragma unroll
        for (int in = 0; in < 4; ++in) {
            const int n = n0 + (tn << 2) + in;
            float bsum = 0.f;
            #pragma unroll
            for (int e = 0; e < NEXP; ++e) bsum += wv[e] * Bias[(size_t)e * Dout + n];
            float v = acc[im][in] + bsum;
            if (act) v = v > 0.f ? v : expm1f(v);
            acc[im][in] = v;
        }
        float4 o = make_float4(acc[im][0], acc[im][1], acc[im][2], acc[im][3]);
        *(float4*)(Y + (size_t)m * Dout + n0 + (tn << 2)) = o;
    }
}

extern "C" void kernel_launch(void* const* d_in, const int* in_sizes, int n_in,
                              void* d_out, int out_size, void* d_ws, size_t ws_size,
                              hipStream_t stream)
{
    (void)in_sizes; (void)n_in; (void)out_size;
    const float* wb = (const float*)d_in[0];
    const float* x  = (const float*)d_in[1];
    const float* W0 = (const float*)d_in[2];
    const float* B0 = (const float*)d_in[3];
    const float* W1 = (const float*)d_in[4];
    const float* B1 = (const float*)d_in[5];
    const float* W2 = (const float*)d_in[6];
    const float* B2 = (const float*)d_in[7];
    float* out = (float*)d_out;

    const size_t NW0 = (size_t)8*1024*512, NW1 = (size_t)8*1024*1024, NW2 = (size_t)8*512*1024;
    const size_t NX0 = (size_t)BATCH*512, NX1 = (size_t)BATCH*1024;
    const size_t need = (NW0 + NW1 + NW2 + NX0 + 2 * NX1) * 2;   // ~44 MB bf16

    if (ws_size >= need) {
        unsigned short* W0p = (unsigned short*)d_ws;
        unsigned short* W1p = W0p + NW0;
        unsigned short* W2p = W1p + NW1;
        unsigned short* x0p = W2p + NW2;
        unsigned short* x1p = x0p + NX0;
        unsigned short* x2p = x1p + NX1;
        pack_all<<<10496, 256, 0, stream>>>(W0, W1, W2, x, W0p, W1p, W2p, x0p);
        moe_mfma6<4><<<dim3(32, 32), 256, 0, stream>>>(x0p, W0p, B0, wb, x1p, 16, 1024, 32, 1, 1);
        moe_mfma6<4><<<dim3(32, 32), 256, 0, stream>>>(x1p, W1p, B1, wb, x2p, 32, 1024, 32, 1, 1);
        moe_mfma6<2><<<dim3(16, 32), 256, 0, stream>>>(x2p, W2p, B2, wb, out, 32, 512,  0, 0, 0);
    } else {
        float* x1 = (float*)d_ws;
        float* x2 = x1 + (size_t)BATCH * 1024;
        moe_layer_f32<<<dim3(1024/BNF, BATCH/BM), 256, 0, stream>>>(x,  W0, B0, wb, x1, 512,  1024, 1);
        moe_layer_f32<<<dim3(1024/BNF, BATCH/BM), 256, 0, stream>>>(x1, W1, B1, wb, x2, 1024, 1024, 1);
        moe_layer_f32<<<dim3(512/BNF,  BATCH/BM), 256, 0, stream>>>(x2, W2, B2, wb, out, 1024, 512,  0);
    }
}